// Round 14
// baseline (74.122 us; speedup 1.0000x reference)
//
#include <hip/hip_runtime.h>

#define S 24
#define PLANE 576
#define CISTRIDE 331776          // floats per (n,ci)
#define SLAB_B 21632             // full padded slab: 676 positions * 32 B
#define QSLAB_B 6656             // quarter window: 8 rows * 26 * 32 B
#define QOFF 4992                // 6 rows * 832 B
#define A_BYTES 46080            // 9 taps * 5 steps * 64 lanes * 16 B
#define WS_SLABS A_BYTES

typedef __attribute__((ext_vector_type(8))) short bf16x8;
typedef __attribute__((ext_vector_type(4))) float f32x4;

__device__ __forceinline__ ushort f2bf(float f) {   // round-to-nearest-even
    unsigned int u = __builtin_bit_cast(unsigned int, f);
    unsigned int r = u + 0x7fffu + ((u >> 16) & 1u);
    return (ushort)(r >> 16);
}

// ---------------- prepass: pure streaming, no LDS, no barriers ----------------
// slab layout: 16B chunk c for (row,col,half): byte = (c*16) ^ ((row&3)<<4), c=(row*26+col)*2+half
__global__ void __launch_bounds__(256)
pack_in(const float* __restrict__ in, const float* __restrict__ wgt, char* __restrict__ ws) {
    const int bid = blockIdx.x;

    if (bid >= 3456) {                   // one extra block: weight A-fragments, 9 taps
        const int t = threadIdx.x;
        for (int i = t; i < 2880; i += 256) {
            int step = i >> 6;           // 0..44
            int tap = step / 5, s = step % 5;
            int lane = i & 63;
            int co = lane & 15, gA = lane >> 4;
            int o = 2 * s + (gA >> 1);
            int cib = (gA & 1) * 8;
            ushort vals[8];
            #pragma unroll
            for (int j = 0; j < 8; ++j)
                vals[j] = (o <= 8) ? f2bf(wgt[co * 1296 + (cib + j) * 81 + tap * 9 + o]) : (ushort)0;
            uint4 pk;
            pk.x = vals[0] | ((unsigned)vals[1] << 16);
            pk.y = vals[2] | ((unsigned)vals[3] << 16);
            pk.z = vals[4] | ((unsigned)vals[5] << 16);
            pk.w = vals[6] | ((unsigned)vals[7] << 16);
            *(uint4*)(ws + (size_t)i * 16) = pk;
        }
        return;
    }

    const int slab = bid / 3;                        // 0..1151
    const int pos  = (bid % 3) * 256 + threadIdx.x;  // 0..767
    if (pos >= 676) return;
    const int nb = slab / PLANE, uv = slab % PLANE;
    const int row = pos / 26, col = pos % 26;
    char* dst = ws + WS_SLABS + (size_t)slab * SLAB_B;
    const int swz = (row & 3) << 4;

    uint4 o0 = make_uint4(0, 0, 0, 0), o1 = o0;
    if (row >= 1 && row <= 24 && col >= 1 && col <= 24) {
        const float* src = in + (size_t)nb * 16 * CISTRIDE + (size_t)uv * PLANE
                              + (row - 1) * 24 + (col - 1);
        float v[16];
        #pragma unroll
        for (int ci = 0; ci < 16; ++ci) v[ci] = src[(size_t)ci * CISTRIDE];
        #pragma unroll
        for (int kk = 0; kk < 4; ++kk) {
            ((unsigned*)&o0)[kk] = (unsigned)f2bf(v[2*kk])     | ((unsigned)f2bf(v[2*kk+1]) << 16);
            ((unsigned*)&o1)[kk] = (unsigned)f2bf(v[8+2*kk])   | ((unsigned)f2bf(v[9+2*kk]) << 16);
        }
    }
    *(uint4*)(dst + (((pos * 2)     * 16) ^ swz)) = o0;
    *(uint4*)(dst + (((pos * 2 + 1) * 16) ^ swz)) = o1;
}

// ---- main: G=4 v-adjacent outputs; each B ds_read feeds up to 3 MFMAs (kv-sharing) ----
__global__ void __launch_bounds__(192, 3)
conv4d_main(const char* __restrict__ ws, const float* __restrict__ bias,
            float* __restrict__ out) {
    __shared__ __align__(16) char lds[2 * QSLAB_B];   // 13312 B double buffer

    const int t = threadIdx.x, lane = t & 63, wvid = t >> 6;   // wave = 8-col band
    // XCD-chunked bijective swizzle: 1152 ids, 8 XCDs x 144 contiguous
    const int braw = blockIdx.x;
    const int b = (braw & 7) * 144 + (braw >> 3);
    const int nb = b / 576, rem = b % 576;
    const int u = rem / 24, rem2 = rem % 24;
    const int v0 = (rem2 >> 2) * 4, qq = rem2 & 3;    // 4 v-slabs, quarter h-band

    const int n16 = lane & 15, g = lane >> 4;
    const int dh = n16 >> 3, dw = n16 & 7;            // 2x8 position tile
    const int half = g & 1, osel = g >> 1;

    // per-(tr,s) B offsets, swizzle phase folded (abs row = qq*6 + tr*2 + dh + kh)
    int loff[3][5];
    #pragma unroll
    for (int tr = 0; tr < 3; ++tr)
        #pragma unroll
        for (int s = 0; s < 5; ++s) {
            int o = 2 * s + osel; if (o > 8) o = 8;   // K-tail clamp (A is zero there)
            int kh = o / 3, kw = o % 3;
            int r_off = dh + kh, c_off = dw + kw;
            int lin = (r_off * 26 + c_off) * 32 + half * 16;
            loff[tr][s] = lin ^ (((qq * 6 + tr * 2 + r_off) & 3) << 4);
        }

    f32x4 acc[4][3];
    #pragma unroll
    for (int a = 0; a < 4; ++a)
        #pragma unroll
        for (int tr = 0; tr < 3; ++tr) acc[a][tr] = (f32x4){0, 0, 0, 0};

    // window mask: i = ku*6 + vj ; uu = u+ku-1, vv = v0+vj-1
    unsigned mask = 0;
    #pragma unroll
    for (int i = 0; i < 18; ++i) {
        int uu = u + i / 6 - 1, vv = v0 + i % 6 - 1;
        if (uu >= 0 && uu < S && vv >= 0 && vv < S) mask |= 1u << i;
    }

    const char* slabs = ws + WS_SLABS;
    const size_t qoff = (size_t)qq * QOFF;
    #define SLAB_PTR(i_) (slabs + ((size_t)nb * PLANE + (u + (i_) / 6 - 1) * S + (v0 + (i_) % 6 - 1)) * SLAB_B + qoff)

    #define STAGE(bufsel_, src_) do {                                              \
        const char* _s = (src_);                                                   \
        _Pragma("unroll")                                                          \
        for (int r2 = 0; r2 < 3; ++r2) {                                           \
            int chunk = r2 * 192 + t;                                              \
            if (r2 < 2 || t < 32)                                                  \
                __builtin_amdgcn_global_load_lds(                                  \
                    (const __attribute__((address_space(1))) unsigned int*)(_s + (size_t)chunk * 16), \
                    (__attribute__((address_space(3))) unsigned int*)(lds + (bufsel_) * QSLAB_B + chunk * 16), \
                    16, 0, 0);                                                     \
        }                                                                          \
    } while (0)

    int first = __ffs(mask) - 1;
    STAGE(0, SLAB_PTR(first));
    __syncthreads();

    int cb = 0;
    bf16x8 afr[3][5];   // A-frags for current ku row (kv = 0..2), all indices static

    #pragma unroll
    for (int ku = 0; ku < 3; ++ku) {
        if (!((mask >> (ku * 6)) & 63u)) continue;    // block-uniform row skip
        #pragma unroll
        for (int kv = 0; kv < 3; ++kv) {
            const char* ap = ws + (size_t)(ku * 3 + kv) * 5120 + (size_t)lane * 16;
            #pragma unroll
            for (int s = 0; s < 5; ++s) afr[kv][s] = *(const bf16x8*)(ap + s * 1024);
        }
        #pragma unroll
        for (int vj = 0; vj < 6; ++vj) {
            const int i = ku * 6 + vj;
            if (!(mask & (1u << i))) continue;        // block-uniform
            unsigned rm = mask >> (i + 1);
            int nx = rm ? (i + 1 + __ffs(rm) - 1) : -1;
            if (nx >= 0) STAGE(cb ^ 1, SLAB_PTR(nx)); // overlaps compute below

            const char* bp = lds + cb * QSLAB_B + wvid * 256;
            #pragma unroll
            for (int tr = 0; tr < 3; ++tr) {
                #pragma unroll
                for (int s = 0; s < 5; ++s) {
                    bf16x8 bfr = *(const bf16x8*)(bp + tr * 1664 + loff[tr][s]);
                    #pragma unroll
                    for (int kv = 0; kv < 3; ++kv) {
                        const int a = vj - kv;        // output slab index
                        if (a >= 0 && a <= 3)
                            acc[a][tr] = __builtin_amdgcn_mfma_f32_16x16x32_bf16(afr[kv][s], bfr, acc[a][tr], 0, 0, 0);
                    }
                }
            }
            __syncthreads();
            cb ^= 1;
        }
    }

    // epilogue: C col = lane&15 -> (dh,dw); row = g*4+r -> c_out ; four v-slabs
    float bv[4];
    #pragma unroll
    for (int r = 0; r < 4; ++r) bv[r] = bias[g * 4 + r];
    #pragma unroll
    for (int a = 0; a < 4; ++a) {
        float* outp = out + (size_t)nb * 16 * CISTRIDE + (size_t)(u * S + v0 + a) * PLANE;
        #pragma unroll
        for (int tr = 0; tr < 3; ++tr) {
            int row = qq * 6 + tr * 2 + dh;
            int col = wvid * 8 + dw;
            int pos = row * S + col;
            #pragma unroll
            for (int r = 0; r < 4; ++r)
                outp[(size_t)(g * 4 + r) * CISTRIDE + pos] = acc[a][tr][r] + bv[r];
        }
    }
}

extern "C" void kernel_launch(void* const* d_in, const int* in_sizes, int n_in,
                              void* d_out, int out_size, void* d_ws, size_t ws_size,
                              hipStream_t stream) {
    const float* in   = (const float*)d_in[0];
    const float* wgt  = (const float*)d_in[1];
    const float* bias = (const float*)d_in[2];
    float* out        = (float*)d_out;
    char* ws          = (char*)d_ws;

    pack_in<<<dim3(3457), dim3(256), 0, stream>>>(in, wgt, ws);
    conv4d_main<<<dim3(1152), dim3(192), 0, stream>>>(ws, bias, out);
}

// Round 15
// 71.623 us; speedup vs baseline: 1.0349x; 1.0349x over previous
//
#include <hip/hip_runtime.h>

#define S 24
#define PLANE 576
#define CISTRIDE 331776          // floats per (n,ci)
#define SLAB_B 21632             // full padded slab: 676 positions * 32 B
#define QSLAB_B 4992             // band window: 6 rows * 26 * 32 B
#define QOFF 3328                // 4 rows * 832 B
#define A_BYTES 46080            // 9 taps * 5 steps * 64 lanes * 16 B
#define WS_SLABS A_BYTES

typedef __attribute__((ext_vector_type(8))) short bf16x8;
typedef __attribute__((ext_vector_type(4))) float f32x4;

__device__ __forceinline__ ushort f2bf(float f) {   // round-to-nearest-even
    unsigned int u = __builtin_bit_cast(unsigned int, f);
    unsigned int r = u + 0x7fffu + ((u >> 16) & 1u);
    return (ushort)(r >> 16);
}

// ---------------- prepass: DMA-staged transpose to bf16 slabs (+ weights from block 0) ----
// slab layout: 16B chunk c for (row,col,half): byte = (c*16) ^ ((row&3)<<4), c=(row*26+col)*2+half
__global__ void __launch_bounds__(256)
pack_in(const float* __restrict__ in, const float* __restrict__ wgt, char* __restrict__ ws) {
    __shared__ __align__(16) float lds_f[16 * 576];   // 36864 B raw f32 planes

    const int b = blockIdx.x;             // 1152 slabs
    const int nb = b / PLANE, uv = b % PLANE;
    const float* src = in + (size_t)nb * 16 * CISTRIDE + (size_t)uv * PLANE;
    char* dst = ws + WS_SLABS + (size_t)b * SLAB_B;
    const int t = threadIdx.x;

    // phase 1: global->LDS DMA, 2304 16B chunks, no VGPR round-trip
    #pragma unroll
    for (int r = 0; r < 9; ++r) {
        int chunk = r * 256 + t;          // exact 9*256
        int ci = chunk / 144, q4 = chunk % 144;
        __builtin_amdgcn_global_load_lds(
            (const __attribute__((address_space(1))) unsigned int*)(src + (size_t)ci * CISTRIDE + 4 * q4),
            (__attribute__((address_space(3))) unsigned int*)(&lds_f[chunk * 4]),
            16, 0, 0);
    }
    __syncthreads();

    // phase 2: convert on read, pack 16 ci per position, swizzled coalesced stores
    #pragma unroll
    for (int i = 0; i < 6; ++i) {
        int c = i * 256 + t;              // chunk index 0..1351
        if (c < 1352) {
            int pos = c >> 1, h = c & 1;
            int row = pos / 26, col = pos % 26;
            uint4 o = make_uint4(0, 0, 0, 0);
            if (row >= 1 && row <= 24 && col >= 1 && col <= 24) {
                int q = (row - 1) * 24 + (col - 1);
                #pragma unroll
                for (int kk = 0; kk < 4; ++kk) {
                    float fa = lds_f[(8 * h + 2 * kk) * 576 + q];
                    float fb = lds_f[(8 * h + 2 * kk + 1) * 576 + q];
                    ((unsigned*)&o)[kk] = (unsigned)f2bf(fa) | ((unsigned)f2bf(fb) << 16);
                }
            }
            *(uint4*)(dst + (((size_t)c * 16) ^ (size_t)((row & 3) << 4))) = o;
        }
    }

    if (b == 0) {                        // weight A-fragments, 9 taps
        for (int i = t; i < 2880; i += 256) {
            int step = i >> 6;           // 0..44
            int tap = step / 5, s = step % 5;
            int lane = i & 63;
            int co = lane & 15, gA = lane >> 4;
            int o = 2 * s + (gA >> 1);
            int cib = (gA & 1) * 8;
            ushort vals[8];
            #pragma unroll
            for (int j = 0; j < 8; ++j)
                vals[j] = (o <= 8) ? f2bf(wgt[co * 1296 + (cib + j) * 81 + tap * 9 + o]) : (ushort)0;
            uint4 pk;
            pk.x = vals[0] | ((unsigned)vals[1] << 16);
            pk.y = vals[2] | ((unsigned)vals[3] << 16);
            pk.z = vals[4] | ((unsigned)vals[5] << 16);
            pk.w = vals[6] | ((unsigned)vals[7] << 16);
            *(uint4*)(ws + (size_t)i * 16) = pk;
        }
    }
}

// ---- main: G=4 v-adjacent outputs, 6 h-bands (4 rows), kv-sharing, 1728 blocks ----
__global__ void __launch_bounds__(192, 4)
conv4d_main(const char* __restrict__ ws, const float* __restrict__ bias,
            float* __restrict__ out) {
    __shared__ __align__(16) char lds[2 * QSLAB_B];   // 9984 B double buffer

    const int t = threadIdx.x, lane = t & 63, wvid = t >> 6;   // wave = 8-col band
    // XCD-chunked bijective swizzle: 1728 ids, 8 XCDs x 216 contiguous
    const int braw = blockIdx.x;
    const int b = (braw & 7) * 216 + (braw >> 3);
    const int nb = b / 864, rem = b % 864;
    const int u = rem / 36, rem2 = rem % 36;
    const int v0 = (rem2 / 6) * 4, qq = rem2 % 6;     // 4 v-slabs, 4-row band

    const int n16 = lane & 15, g = lane >> 4;
    const int dh = n16 >> 3, dw = n16 & 7;            // 2x8 position tile
    const int half = g & 1, osel = g >> 1;

    // per-(tr,s) B offsets; band base row = 4*qq ≡ 0 mod 4 -> phase = (2*tr + r_off)&3
    int loff[2][5];
    #pragma unroll
    for (int tr = 0; tr < 2; ++tr)
        #pragma unroll
        for (int s = 0; s < 5; ++s) {
            int o = 2 * s + osel; if (o > 8) o = 8;   // K-tail clamp (A is zero there)
            int kh = o / 3, kw = o % 3;
            int r_off = dh + kh, c_off = dw + kw;
            int lin = (r_off * 26 + c_off) * 32 + half * 16;
            loff[tr][s] = lin ^ (((tr * 2 + r_off) & 3) << 4);
        }

    f32x4 acc[4][2];
    #pragma unroll
    for (int a = 0; a < 4; ++a)
        #pragma unroll
        for (int tr = 0; tr < 2; ++tr) acc[a][tr] = (f32x4){0, 0, 0, 0};

    // window mask: i = ku*6 + vj ; uu = u+ku-1, vv = v0+vj-1
    unsigned mask = 0;
    #pragma unroll
    for (int i = 0; i < 18; ++i) {
        int uu = u + i / 6 - 1, vv = v0 + i % 6 - 1;
        if (uu >= 0 && uu < S && vv >= 0 && vv < S) mask |= 1u << i;
    }

    const char* slabs = ws + WS_SLABS;
    const size_t qoff = (size_t)qq * QOFF;
    #define SLAB_PTR(i_) (slabs + ((size_t)nb * PLANE + (u + (i_) / 6 - 1) * S + (v0 + (i_) % 6 - 1)) * SLAB_B + qoff)

    #define STAGE(bufsel_, src_) do {                                              \
        const char* _s = (src_);                                                   \
        _Pragma("unroll")                                                          \
        for (int r2 = 0; r2 < 2; ++r2) {                                           \
            int chunk = r2 * 192 + t;                                              \
            if (r2 < 1 || t < 120)                                                 \
                __builtin_amdgcn_global_load_lds(                                  \
                    (const __attribute__((address_space(1))) unsigned int*)(_s + (size_t)chunk * 16), \
                    (__attribute__((address_space(3))) unsigned int*)(lds + (bufsel_) * QSLAB_B + chunk * 16), \
                    16, 0, 0);                                                     \
        }                                                                          \
    } while (0)

    int first = __ffs(mask) - 1;
    STAGE(0, SLAB_PTR(first));
    __syncthreads();

    int cb = 0;
    bf16x8 afr[3][5];   // A-frags for current ku row (kv = 0..2), all indices static

    #pragma unroll
    for (int ku = 0; ku < 3; ++ku) {
        if (!((mask >> (ku * 6)) & 63u)) continue;    // block-uniform row skip
        #pragma unroll
        for (int kv = 0; kv < 3; ++kv) {
            const char* ap = ws + (size_t)(ku * 3 + kv) * 5120 + (size_t)lane * 16;
            #pragma unroll
            for (int s = 0; s < 5; ++s) afr[kv][s] = *(const bf16x8*)(ap + s * 1024);
        }
        #pragma unroll
        for (int vj = 0; vj < 6; ++vj) {
            const int i = ku * 6 + vj;
            if (!(mask & (1u << i))) continue;        // block-uniform
            unsigned rm = mask >> (i + 1);
            int nx = rm ? (i + 1 + __ffs(rm) - 1) : -1;
            if (nx >= 0) STAGE(cb ^ 1, SLAB_PTR(nx)); // overlaps compute below

            const char* bp = lds + cb * QSLAB_B + wvid * 256;
            #pragma unroll
            for (int tr = 0; tr < 2; ++tr) {
                #pragma unroll
                for (int s = 0; s < 5; ++s) {
                    bf16x8 bfr = *(const bf16x8*)(bp + tr * 1664 + loff[tr][s]);
                    #pragma unroll
                    for (int kv = 0; kv < 3; ++kv) {
                        const int a = vj - kv;        // output slab index
                        if (a >= 0 && a <= 3)
                            acc[a][tr] = __builtin_amdgcn_mfma_f32_16x16x32_bf16(afr[kv][s], bfr, acc[a][tr], 0, 0, 0);
                    }
                }
            }
            __syncthreads();
            cb ^= 1;
        }
    }

    // epilogue: C col = lane&15 -> (dh,dw); row = g*4+r -> c_out ; four v-slabs
    float bv[4];
    #pragma unroll
    for (int r = 0; r < 4; ++r) bv[r] = bias[g * 4 + r];
    #pragma unroll
    for (int a = 0; a < 4; ++a) {
        float* outp = out + (size_t)nb * 16 * CISTRIDE + (size_t)(u * S + v0 + a) * PLANE;
        #pragma unroll
        for (int tr = 0; tr < 2; ++tr) {
            int row = qq * 4 + tr * 2 + dh;
            int col = wvid * 8 + dw;
            int pos = row * S + col;
            #pragma unroll
            for (int r = 0; r < 4; ++r)
                outp[(size_t)(g * 4 + r) * CISTRIDE + pos] = acc[a][tr][r] + bv[r];
        }
    }
}

extern "C" void kernel_launch(void* const* d_in, const int* in_sizes, int n_in,
                              void* d_out, int out_size, void* d_ws, size_t ws_size,
                              hipStream_t stream) {
    const float* in   = (const float*)d_in[0];
    const float* wgt  = (const float*)d_in[1];
    const float* bias = (const float*)d_in[2];
    float* out        = (float*)d_out;
    char* ws          = (char*)d_ws;

    pack_in<<<dim3(1152), dim3(256), 0, stream>>>(in, wgt, ws);
    conv4d_main<<<dim3(1728), dim3(192), 0, stream>>>(ws, bias, out);
}